// Round 1
// baseline (44.958 us; speedup 1.0000x reference)
//
#include <hip/hip_runtime.h>
#include <math.h>

#define PP 9       // K*K
#define CAPS 32
#define PS 16
#define HPS 8      // pose elems per thread (PS split across 2 threads)
#define OH 15
#define HH 32
#define WW 32
#define LN_2PI 1.8378770664093453f

__device__ __forceinline__ float frcp(float x) {
    float r;
    asm("v_rcp_f32 %0, %1" : "=v"(r) : "v"(x));
    return r;
}

// DPP helpers (VALU pipe): quad_perm xor1=0xB1, xor2=0x4E; row_ror:4=0x124, row_ror:8=0x128.
template <int CTRL>
__device__ __forceinline__ float dppf(float x) {
    int r = __builtin_amdgcn_update_dpp(0, __builtin_bit_cast(int, x), CTRL, 0xF, 0xF, true);
    return __builtin_bit_cast(float, r);
}
__device__ __forceinline__ float row_sum16(float x) {
    x += dppf<0xB1>(x);
    x += dppf<0x4E>(x);
    x += dppf<0x124>(x);
    x += dppf<0x128>(x);
    return x;
}
__device__ __forceinline__ float row_max16(float x) {
    x = fmaxf(x, dppf<0xB1>(x));
    x = fmaxf(x, dppf<0x4E>(x));
    x = fmaxf(x, dppf<0x124>(x));
    x = fmaxf(x, dppf<0x128>(x));
    return x;
}
// xor16 within each 32-lane group (and-mask 0x1F) -> halves stay independent.
__device__ __forceinline__ float swz_xor16(float x) {
    return __builtin_bit_cast(float,
        __builtin_amdgcn_ds_swizzle(__builtin_bit_cast(int, x), 0x401F));
}
// exchange with lane^32 (ds_bpermute spans the full 64-lane wave)
__device__ __forceinline__ float xhalf(float x) {
    return __shfl_xor(x, 32);
}

// One 64-lane wave = ONE site. lane = half*32 + c.
// Each thread owns 8 of the 16 pose elements of capsule c (t = half*8 + u).
// This halves per-thread register state (v[9][8] instead of v[9][16]) so the
// whole kernel fits in <=128 arch VGPRs: 4 waves/SIMD, no AGPR spill copies.
// Softmax over the 32 capsules stays inside each 32-lane half (both halves
// redundantly compute identical r[k]/a_out; cross-half adds are commutative
// so the halves agree bitwise). Cross-half sums: 9 shfl_xor(32) per E-step
// (ln-p partial over t) + 1 per M-step (sum of log sigma).
__global__ __launch_bounds__(64, 4) void emcaps_kernel(
    const float* __restrict__ x,      // (32,32,32,32,16)
    const float* __restrict__ a,      // (32,32,32,32)
    const float* __restrict__ wgt,    // (9,32,4,4)
    const float* __restrict__ beta_u, // (32)
    const float* __restrict__ beta_a, // (32)
    float* __restrict__ out_mu,       // (32,15,15,32,16)
    float* __restrict__ out_a)        // (32,15,15,32)
{
    const int lane = threadIdx.x;   // 0..63
    const int half = lane >> 5;     // which 8 pose elems
    const int c = lane & 31;        // capsule

    const int site = blockIdx.x;
    const int j = site % OH;
    const int t2 = site / OH;
    const int i = t2 % OH;
    const int b = t2 / OH;
    const int h0 = 2 * i, w0 = 2 * j;

    // ---- phase 1: all global loads issued back-to-back ----
    float v[PP][HPS];  // holds x now; overwritten with votes in phase 2
    float r[PP];
    #pragma unroll
    for (int k = 0; k < PP; ++k) {
        const int hh = h0 + k / 3, ww = w0 + k % 3;
        const size_t pix = (size_t)(b * HH + hh) * WW + ww;
        const float* xb = x + pix * (CAPS * PS) + c * PS + half * HPS;
        *(float4*)&v[k][0] = *(const float4*)xb;
        *(float4*)&v[k][4] = *(const float4*)(xb + 4);
        r[k] = a[pix * CAPS + c] * (1.f / 32.f);  // initial r (it0)
    }

    // ---- phase 2: votes in place (weights are L1-hot: 18 KB total) ----
    // t = half*8 + u, p = t>>2, q-col = t&3:
    // vote[t] = sum_q x[p][q] * w[q][t&3]; x[p][q] lives at local (u&4)+q.
    #pragma unroll
    for (int k = 0; k < PP; ++k) {
        float xt[HPS];
        #pragma unroll
        for (int u = 0; u < HPS; ++u) xt[u] = v[k][u];
        float wl[PS];
        const float* wb = wgt + k * (CAPS * PS) + c * PS;
        *(float4*)&wl[0]  = *(const float4*)wb;
        *(float4*)&wl[4]  = *(const float4*)(wb + 4);
        *(float4*)&wl[8]  = *(const float4*)(wb + 8);
        *(float4*)&wl[12] = *(const float4*)(wb + 12);
        #pragma unroll
        for (int u = 0; u < HPS; ++u) {
            float acc = 0.f;
            #pragma unroll
            for (int q = 0; q < 4; ++q)
                acc = fmaf(xt[(u & 4) + q], wl[q * 4 + (u & 3)], acc);
            v[k][u] = acc;
        }
    }

    const float bu = beta_u[c];
    const float ba = beta_a[c];
    const float eps = 1e-6f;
    const float lam = 1e-3f;

    float mu[HPS], is2[HPS];   // is2 = 1/(2*sigma^2); sigma itself not kept
    float aoc = 0.f;
    float slgfull = 0.f;       // full sum over 16 t of 0.5*log(sigma^2)
    float r_sum;

    for (int it = 0; it < 3; ++it) {
        if (it > 0) {
            // ---- E-step ----
            const float addc = __logf(aoc) - slgfull - 8.f * LN_2PI;
            #pragma unroll
            for (int k = 0; k < PP; ++k) {
                float sacc = 0.f;
                #pragma unroll
                for (int u = 0; u < HPS; ++u) {
                    float d = v[k][u] - mu[u];
                    sacc = fmaf(d * d, is2[u], sacc);
                }
                sacc += xhalf(sacc);         // full 16-element sum
                const float lnk = addc - sacc;
                // softmax over c within this 32-lane half
                float mx = row_max16(lnk);
                mx = fmaxf(mx, swz_xor16(mx));
                float e = __expf(lnk - mx);
                float ss = row_sum16(e);
                ss += swz_xor16(ss);
                r[k] = e * frcp(ss);
            }
        }

        // ---- M-step: two-pass (numerically required) ----
        r_sum = 0.f;
        #pragma unroll
        for (int k = 0; k < PP; ++k) r_sum += r[k];
        const float invr = frcp(r_sum + eps);
        #pragma unroll
        for (int k = 0; k < PP; ++k) r[k] *= invr;  // coeff

        #pragma unroll
        for (int u = 0; u < HPS; ++u) {
            float m = 0.f;
            #pragma unroll
            for (int k = 0; k < PP; ++k) m = fmaf(r[k], v[k][u], m);
            mu[u] = m;
        }
        float slg = 0.f;
        #pragma unroll
        for (int u = 0; u < HPS; ++u) {
            float sacc = 0.f;
            #pragma unroll
            for (int k = 0; k < PP; ++k) {
                float d = v[k][u] - mu[u];
                sacc = fmaf(r[k] * d, d, sacc);
            }
            const float sg = sacc + eps;
            is2[u] = frcp(2.f * sg);
            slg += 0.5f * __logf(sg);
        }
        slgfull = slg + xhalf(slg);          // full 16-element sum
        const float ch = r_sum * (16.f * bu + slgfull);
        aoc = frcp(1.f + __expf(-lam * (ba - ch)));
    }

    // ---- outputs: each thread stores its 8 mu's (32B); half 0 stores a ----
    float* ob = out_mu + (size_t)site * (CAPS * PS) + c * PS + half * HPS;
    *(float4*)(ob + 0) = make_float4(mu[0], mu[1], mu[2], mu[3]);
    *(float4*)(ob + 4) = make_float4(mu[4], mu[5], mu[6], mu[7]);
    if (half == 0) out_a[(size_t)site * CAPS + c] = aoc;
}

extern "C" void kernel_launch(void* const* d_in, const int* in_sizes, int n_in,
                              void* d_out, int out_size, void* d_ws, size_t ws_size,
                              hipStream_t stream) {
    const float* x      = (const float*)d_in[0];
    const float* a      = (const float*)d_in[1];
    const float* wgt    = (const float*)d_in[2];
    const float* beta_u = (const float*)d_in[3];
    const float* beta_a = (const float*)d_in[4];

    float* out_mu = (float*)d_out;
    float* out_a  = (float*)d_out + (size_t)32 * OH * OH * CAPS * PS;  // 3,686,400

    const int n_sites = 32 * OH * OH;  // 7200
    emcaps_kernel<<<n_sites, 64, 0, stream>>>(x, a, wgt, beta_u, beta_a, out_mu, out_a);
}